// Round 4
// baseline (103.114 us; speedup 1.0000x reference)
//
#include <hip/hip_runtime.h>
#include <hip/hip_bf16.h>

// 2:4 structured pruning: per contiguous block of 4 floats keep the 2
// largest-|x| (ties -> lower index, matching jax.lax.top_k), zero the rest.
// Pure streaming op (256 MiB in + 256 MiB out, zero reuse).
// Structure: exact grid, TWO float4s per thread from two contiguous streams
// offset by half the array (perfect 16B/lane coalescing per instruction),
// load-load-store-store for 2x memory-level parallelism per thread and half
// the wave count vs one-shot. No loop.

typedef float f32x4 __attribute__((ext_vector_type(4)));

__device__ __forceinline__ f32x4 prune4(f32x4 v) {
    const float a0 = fabsf(v.x), a1 = fabsf(v.y),
                a2 = fabsf(v.z), a3 = fabsf(v.w);
    // rank_i = #{j beats i}; j beats i if a_j > a_i, or a_j == a_i && j < i.
    const int r0 = (a1 > a0) + (a2 > a0) + (a3 > a0);
    const int r1 = (a0 >= a1) + (a2 > a1) + (a3 > a1);
    const int r2 = (a0 >= a2) + (a1 >= a2) + (a3 > a2);
    const int r3 = (a0 >= a3) + (a1 >= a3) + (a2 >= a3);
    v.x = (r0 < 2) ? v.x : 0.0f;
    v.y = (r1 < 2) ? v.y : 0.0f;
    v.z = (r2 < 2) ? v.z : 0.0f;
    v.w = (r3 < 2) ? v.w : 0.0f;
    return v;
}

__global__ __launch_bounds__(256) void Sparsity_48009144435553_kernel(
    const f32x4* __restrict__ in, f32x4* __restrict__ out,
    const int* __restrict__ um, const int* __restrict__ am,
    long long half) {
    const long long i = (long long)blockIdx.x * 256 + threadIdx.x;
    // two independent loads in flight before any use
    f32x4 v0 = in[i];
    f32x4 v1 = in[i + half];
    const bool prune = (um[0] != 0) && (am[0] != 0);
    if (prune) { v0 = prune4(v0); v1 = prune4(v1); }
    out[i] = v0;
    out[i + half] = v1;
}

// generic tail (not hit at 8192^2, kept for generality)
__global__ __launch_bounds__(256) void Sparsity_tail_kernel(
    const float* __restrict__ in, float* __restrict__ out,
    long long start, long long n) {
    const long long i = start + (long long)blockIdx.x * 256 + threadIdx.x;
    if (i < n) out[i] = in[i];
}

extern "C" void kernel_launch(void* const* d_in, const int* in_sizes, int n_in,
                              void* d_out, int out_size, void* d_ws, size_t ws_size,
                              hipStream_t stream) {
    const f32x4* in = (const f32x4*)d_in[0];
    const int* um = (const int*)d_in[1];
    const int* am = (const int*)d_in[2];
    f32x4* out = (f32x4*)d_out;

    const long long n = (long long)in_sizes[0];
    const long long nblk = n / 4;                  // 16M float4 blocks
    const long long half = nblk / 2;               // 8M
    const long long nwg = half / 256;              // 32768 workgroups, exact

    Sparsity_48009144435553_kernel<<<(int)nwg, 256, 0, stream>>>(in, out, um, am, half);

    const long long done = nwg * 256 * 2 * 4;      // elements covered
    if (done < n) {
        const long long rem = n - done;
        const int tgrid = (int)((rem + 255) / 256);
        Sparsity_tail_kernel<<<tgrid, 256, 0, stream>>>(
            (const float*)d_in[0], (float*)d_out, done, n);
    }
}

// Round 5
// 98.533 us; speedup vs baseline: 1.0465x; 1.0465x over previous
//
#include <hip/hip_runtime.h>
#include <hip/hip_bf16.h>

// 2:4 structured pruning: per contiguous block of 4 floats keep the 2
// largest-|x| (ties -> lower index, matching jax.lax.top_k), zero the rest.
// Pure streaming op (256 MiB in + 256 MiB out, zero reuse).
// Structure: exact grid, no loop, 32 B CONTIGUOUS per thread (two float4s at
// offsets 0/16 from one base). Lessons from R2/R4: far-apart streams per wave
// hurt DRAM locality; adjacent pairs keep each wave's footprint one contiguous
// 2 KiB span while halving wave+workgroup count and giving 2 loads in flight.

typedef float f32x4 __attribute__((ext_vector_type(4)));

__device__ __forceinline__ f32x4 prune4(f32x4 v) {
    const float a0 = fabsf(v.x), a1 = fabsf(v.y),
                a2 = fabsf(v.z), a3 = fabsf(v.w);
    // rank_i = #{j beats i}; j beats i if a_j > a_i, or a_j == a_i && j < i.
    const int r0 = (a1 > a0) + (a2 > a0) + (a3 > a0);
    const int r1 = (a0 >= a1) + (a2 > a1) + (a3 > a1);
    const int r2 = (a0 >= a2) + (a1 >= a2) + (a3 > a2);
    const int r3 = (a0 >= a3) + (a1 >= a3) + (a2 >= a3);
    v.x = (r0 < 2) ? v.x : 0.0f;
    v.y = (r1 < 2) ? v.y : 0.0f;
    v.z = (r2 < 2) ? v.z : 0.0f;
    v.w = (r3 < 2) ? v.w : 0.0f;
    return v;
}

__global__ __launch_bounds__(256) void Sparsity_48009144435553_kernel(
    const f32x4* __restrict__ in, f32x4* __restrict__ out,
    const int* __restrict__ um, const int* __restrict__ am) {
    const long long i = 2 * ((long long)blockIdx.x * 256 + threadIdx.x);
    // two adjacent loads from one base address, both in flight before use
    f32x4 v0 = in[i];
    f32x4 v1 = in[i + 1];
    if ((um[0] != 0) && (am[0] != 0)) { v0 = prune4(v0); v1 = prune4(v1); }
    out[i] = v0;
    out[i + 1] = v1;
}

// generic tail (not hit at 8192^2, kept for generality)
__global__ __launch_bounds__(256) void Sparsity_tail_kernel(
    const float* __restrict__ in, float* __restrict__ out,
    long long start, long long n) {
    const long long i = start + (long long)blockIdx.x * 256 + threadIdx.x;
    if (i < n) out[i] = in[i];
}

extern "C" void kernel_launch(void* const* d_in, const int* in_sizes, int n_in,
                              void* d_out, int out_size, void* d_ws, size_t ws_size,
                              hipStream_t stream) {
    const f32x4* in = (const f32x4*)d_in[0];
    const int* um = (const int*)d_in[1];
    const int* am = (const int*)d_in[2];
    f32x4* out = (f32x4*)d_out;

    const long long n = (long long)in_sizes[0];
    const long long nblk = n / 4;                  // 16M float4 blocks
    const long long nwg = nblk / (2 * 256);        // 32768 workgroups, exact

    Sparsity_48009144435553_kernel<<<(int)nwg, 256, 0, stream>>>(in, out, um, am);

    const long long done = nwg * 256 * 2 * 4;      // elements covered
    if (done < n) {
        const long long rem = n - done;
        const int tgrid = (int)((rem + 255) / 256);
        Sparsity_tail_kernel<<<tgrid, 256, 0, stream>>>(
            (const float*)d_in[0], (float*)d_out, done, n);
    }
}

// Round 6
// 93.040 us; speedup vs baseline: 1.1083x; 1.0590x over previous
//
#include <hip/hip_runtime.h>
#include <hip/hip_bf16.h>

// 2:4 structured pruning: per contiguous block of 4 floats keep the 2
// largest-|x| (ties -> lower index, matching jax.lax.top_k), zero the rest.
// Pure streaming op (256 MiB in + 256 MiB out, zero reuse). Best measured
// structure (R3, 94.7 us = 5.67 TB/s, 90% of the 6.29 TB/s copy ceiling):
// exact grid, ONE float4 per thread, no loop. All attempted refinements
// regressed: grid-stride loop (106us), nt+4-unroll (111us), two far streams
// (103us), two adjacent float4s (98.5us). Keep it minimal.

typedef float f32x4 __attribute__((ext_vector_type(4)));

__device__ __forceinline__ f32x4 prune4(f32x4 v) {
    const float a0 = fabsf(v.x), a1 = fabsf(v.y),
                a2 = fabsf(v.z), a3 = fabsf(v.w);
    // rank_i = #{j beats i}; j beats i if a_j > a_i, or a_j == a_i && j < i.
    const int r0 = (a1 > a0) + (a2 > a0) + (a3 > a0);
    const int r1 = (a0 >= a1) + (a2 > a1) + (a3 > a1);
    const int r2 = (a0 >= a2) + (a1 >= a2) + (a3 > a2);
    const int r3 = (a0 >= a3) + (a1 >= a3) + (a2 >= a3);
    v.x = (r0 < 2) ? v.x : 0.0f;
    v.y = (r1 < 2) ? v.y : 0.0f;
    v.z = (r2 < 2) ? v.z : 0.0f;
    v.w = (r3 < 2) ? v.w : 0.0f;
    return v;
}

__global__ __launch_bounds__(256) void Sparsity_48009144435553_kernel(
    const f32x4* __restrict__ in, f32x4* __restrict__ out,
    const int* __restrict__ um, const int* __restrict__ am) {
    const long long i = (long long)blockIdx.x * 256 + threadIdx.x;
    f32x4 v = in[i];
    if ((um[0] != 0) && (am[0] != 0)) v = prune4(v);
    out[i] = v;
}

// tail kernel for sizes not divisible by 4*256 (not hit at 8192^2, kept for
// generality)
__global__ __launch_bounds__(256) void Sparsity_tail_kernel(
    const float* __restrict__ in, float* __restrict__ out,
    long long start, long long n) {
    const long long i = start + (long long)blockIdx.x * 256 + threadIdx.x;
    if (i < n) out[i] = in[i];
}

extern "C" void kernel_launch(void* const* d_in, const int* in_sizes, int n_in,
                              void* d_out, int out_size, void* d_ws, size_t ws_size,
                              hipStream_t stream) {
    const f32x4* in = (const f32x4*)d_in[0];
    const int* um = (const int*)d_in[1];
    const int* am = (const int*)d_in[2];
    f32x4* out = (f32x4*)d_out;

    const long long n = (long long)in_sizes[0];
    const long long nblk = n / 4;                 // 16M float4 blocks
    const long long nwg = nblk / 256;             // 65536 workgroups, exact

    Sparsity_48009144435553_kernel<<<(int)nwg, 256, 0, stream>>>(in, out, um, am);

    const long long done = nwg * 256 * 4;
    if (done < n) {
        const long long rem = n - done;
        const int tgrid = (int)((rem + 255) / 256);
        Sparsity_tail_kernel<<<tgrid, 256, 0, stream>>>(
            (const float*)d_in[0], (float*)d_out, done, n);
    }
}